// Round 4
// baseline (89.679 us; speedup 1.0000x reference)
//
#include <hip/hip_runtime.h>

namespace {
constexpr int Wd = 160, Hd = 192, Dd = 160, Bd = 2;
constexpr int HW = Hd * Wd;
constexpr int THREADS = 320;              // 5 waves; 8 rows x 40 strips, ALL threads compute
constexpr int ROWS_OUT = 8;
constexpr int ROWS_LDS = 10;              // incl. h-halo
constexpr int STRIPS = 40;
constexpr int RS = 164;                   // LDS row stride (floats); 164%32=4 -> rows shift banks
constexpr int DCHUNK = 10;
constexpr int NCHUNK = Dd / DCHUNK;       // 16
constexpr int HGROUPS = Hd / ROWS_OUT;    // 24
constexpr int NTASK = 2 * ROWS_LDS * STRIPS;  // 800 staging tasks (2 tensors)
constexpr float EPS = 1e-8f;
}

__global__ __launch_bounds__(THREADS) void sobel_loss_kernel(
    const float* __restrict__ pred, const float* __restrict__ targ,
    float* __restrict__ out) {
  // [tensor][arr: 0=sw,1=dw][row][RS] — 26.2 KB
  __shared__ float lds[2][2][ROWS_LDS][RS];
  const int tid = threadIdx.x;
  const int h0 = blockIdx.x * ROWS_OUT;
  const int d0 = blockIdx.y * DCHUNK;
  const size_t volOff = (size_t)blockIdx.z * Dd * HW;
  const float* pb = pred + volOff;
  const float* tb = targ + volOff;

  // ---- staging task decode (2.5 tasks/thread, loop-invariant) ----
  const float* gp[3];
  float* dsw[3];
  float* ddw[3];
  bool okv[3], rvv[3], sl0[3], sr39[3];
#pragma unroll
  for (int u = 0; u < 3; ++u) {
    const int idx = tid + THREADS * u;
    const bool ok = (idx < NTASK);
    const int ic = ok ? idx : 0;
    const int t_ = ic / (ROWS_LDS * STRIPS);
    const int rem = ic - t_ * (ROWS_LDS * STRIPS);
    const int r8 = rem / STRIPS;
    const int s = rem - r8 * STRIPS;
    const int hh = h0 - 1 + r8;
    const bool rv = ok && ((unsigned)hh < (unsigned)Hd);
    okv[u] = ok; rvv[u] = rv;
    sl0[u] = (s > 0); sr39[u] = (s < STRIPS - 1);
    gp[u] = (t_ ? tb : pb) + (size_t)(rv ? hh : 0) * Wd + s * 4;
    dsw[u] = &lds[t_][0][r8][s * 4];
    ddw[u] = &lds[t_][1][r8][s * 4];
  }

  float4 xm[3]; float xlv[3], xrv[3];

  auto GLOADX = [&](int d) {   // issue-only: fill xm/xlv/xrv for slice d
    const bool dok = (unsigned)d < (unsigned)Dd;
    const size_t so = (size_t)d * HW;
#pragma unroll
    for (int u = 0; u < 3; ++u) {
      float4 v = make_float4(0.f, 0.f, 0.f, 0.f);
      float l = 0.f, rr = 0.f;
      if (dok && rvv[u]) {
        v = *reinterpret_cast<const float4*>(gp[u] + so);
        if (sl0[u]) l = gp[u][so - 1];
        if (sr39[u]) rr = gp[u][so + 4];
      }
      xm[u] = v; xlv[u] = l; xrv[u] = rr;
    }
  };

  auto STAGE = [&]() {   // consume xm/xlv/xrv: w-conv in regs, write sw/dw to LDS
#pragma unroll
    for (int u = 0; u < 3; ++u) {
      const float x0 = xlv[u], x1 = xm[u].x, x2 = xm[u].y, x3 = xm[u].z,
                  x4 = xm[u].w, x5 = xrv[u];
      float4 swv, dwv;
      swv.x = x0 + 2.f * x1 + x2;  dwv.x = x2 - x0;
      swv.y = x1 + 2.f * x2 + x3;  dwv.y = x3 - x1;
      swv.z = x2 + 2.f * x3 + x4;  dwv.z = x4 - x2;
      swv.w = x3 + 2.f * x4 + x5;  dwv.w = x5 - x3;
      if (okv[u]) {
        *reinterpret_cast<float4*>(dsw[u]) = swv;
        *reinterpret_cast<float4*>(ddw[u]) = dwv;
      }
    }
  };

  // ---- compute decode: output row r (0..7), strip (0..39) ----
  const int r = tid / STRIPS;
  const int s4 = (tid - r * STRIPS) * 4;

  // rolling state [slot][tensor][j]
  float A[3][2][4], B[3][2][4], C[3][2][4];

  auto HCONV = [&](int slot) {
#pragma unroll
    for (int t_ = 0; t_ < 2; ++t_) {
      const float4 sm = *reinterpret_cast<const float4*>(&lds[t_][0][r][s4]);
      const float4 s0 = *reinterpret_cast<const float4*>(&lds[t_][0][r + 1][s4]);
      const float4 sp = *reinterpret_cast<const float4*>(&lds[t_][0][r + 2][s4]);
      const float4 dm = *reinterpret_cast<const float4*>(&lds[t_][1][r][s4]);
      const float4 dd = *reinterpret_cast<const float4*>(&lds[t_][1][r + 1][s4]);
      const float4 dp = *reinterpret_cast<const float4*>(&lds[t_][1][r + 2][s4]);
      const float smv[4] = {sm.x, sm.y, sm.z, sm.w};
      const float s0v[4] = {s0.x, s0.y, s0.z, s0.w};
      const float spv[4] = {sp.x, sp.y, sp.z, sp.w};
      const float dmv[4] = {dm.x, dm.y, dm.z, dm.w};
      const float ddv[4] = {dd.x, dd.y, dd.z, dd.w};
      const float dpv[4] = {dp.x, dp.y, dp.z, dp.w};
#pragma unroll
      for (int j = 0; j < 4; ++j) {
        A[slot][t_][j] = smv[j] + 2.f * s0v[j] + spv[j];
        B[slot][t_][j] = dmv[j] + 2.f * ddv[j] + dpv[j];
        C[slot][t_][j] = spv[j] - smv[j];
      }
    }
  };

  float acc = 0.f;

  // ---- prologue ----
  GLOADX(d0 - 1);
  STAGE();                                   // LDS <- slice d0-1 (consume)
  GLOADX(d0);                                // issue
  __syncthreads();
  HCONV(0);                                  // state0 <- slice d0-1 (covering phase)
  __syncthreads();
  STAGE();                                   // LDS <- slice d0
  GLOADX(d0 + 1);
  __syncthreads();
  HCONV(1);                                  // state1 <- slice d0
  __syncthreads();

  // ---- main loop, fully unrolled: output slice d0+k ----
#pragma unroll
  for (int k = 0; k < DCHUNK; ++k) {
    STAGE();                                 // LDS <- slice d0+1+k (consume prev loads)
    if (k < DCHUNK - 1) GLOADX(d0 + 2 + k);  // issue next (consumed next iter top)
    __syncthreads();
    const int i0 = k % 3, i1 = (k + 1) % 3, i2 = (k + 2) % 3;
    HCONV(i2);                               // state <- slice d0+1+k
#pragma unroll
    for (int j = 0; j < 4; ++j) {
      float gx = B[i0][0][j] + 2.f * B[i1][0][j] + B[i2][0][j];
      float gy = C[i0][0][j] + 2.f * C[i1][0][j] + C[i2][0][j];
      float gz = A[i2][0][j] - A[i0][0][j];
      const float pm = sqrtf(fmaf(gx, gx, fmaf(gy, gy, fmaf(gz, gz, EPS))));
      gx = B[i0][1][j] + 2.f * B[i1][1][j] + B[i2][1][j];
      gy = C[i0][1][j] + 2.f * C[i1][1][j] + C[i2][1][j];
      gz = A[i2][1][j] - A[i0][1][j];
      const float tm = sqrtf(fmaf(gx, gx, fmaf(gy, gy, fmaf(gz, gz, EPS))));
      acc += fabsf(pm - tm);
    }
    __syncthreads();
  }

  // ---- reduction: wave shfl -> LDS -> one atomic per block ----
  float sred = acc;
#pragma unroll
  for (int off = 32; off > 0; off >>= 1) sred += __shfl_down(sred, off, 64);
  __shared__ float wsum[THREADS / 64];
  const int lane = tid & 63;
  const int wid = tid >> 6;
  if (lane == 0) wsum[wid] = sred;
  __syncthreads();
  if (tid == 0) {
    float t = 0.f;
#pragma unroll
    for (int i = 0; i < THREADS / 64; ++i) t += wsum[i];
    atomicAdd(out, t * (1.0f / (float)((size_t)Bd * Dd * Hd * Wd)));
  }
}

extern "C" void kernel_launch(void* const* d_in, const int* in_sizes, int n_in,
                              void* d_out, int out_size, void* d_ws, size_t ws_size,
                              hipStream_t stream) {
  const float* pred = (const float*)d_in[0];
  const float* targ = (const float*)d_in[1];
  float* out = (float*)d_out;
  (void)in_sizes; (void)n_in; (void)out_size; (void)d_ws; (void)ws_size;

  hipMemsetAsync(out, 0, sizeof(float), stream);
  dim3 grid(HGROUPS, NCHUNK, Bd);
  sobel_loss_kernel<<<grid, THREADS, 0, stream>>>(pred, targ, out);
}

// Round 5
// 49.857 us; speedup vs baseline: 1.7987x; 1.7987x over previous
//
#include <hip/hip_runtime.h>

namespace {
constexpr int Wd = 160, Hd = 192, Dd = 160, Bd = 2;
constexpr int HW = Hd * Wd;
constexpr int THREADS = 256;               // 4 waves — even SIMD split (proven R2)
constexpr int ROWS_OUT = 6;                // output rows per block
constexpr int ROWS_LDS = 8;                // staged rows incl. h-halo
constexpr int RS = 168;                    // LDS row stride; data at [4..163], pads at 3,164
constexpr int STRIPS = Wd / 4;             // 40 float4 strips per row
constexpr int CTHREADS = ROWS_OUT * STRIPS;   // 240 compute threads
constexpr int SLOTS = 2 * ROWS_LDS * STRIPS;  // 640 staging float4 slots (2 tensors)
constexpr int DCHUNK = 8;                  // smaller chunk -> 1280 blocks = 5/CU
constexpr int NCHUNK = Dd / DCHUNK;        // 20
constexpr int RGROUPS = Hd / ROWS_OUT;     // 32
constexpr float EPS = 1e-8f;
}

__global__ __launch_bounds__(THREADS) void sobel_loss_kernel(
    const float* __restrict__ pred, const float* __restrict__ targ,
    float* __restrict__ out) {
  __shared__ float lds[2][ROWS_LDS][RS];
  const int tid = threadIdx.x;
  const int h0 = blockIdx.x * ROWS_OUT;
  const int d0 = blockIdx.y * DCHUNK;
  const size_t volOff = (size_t)blockIdx.z * Dd * HW;
  const float* pb = pred + volOff;
  const float* tb = targ + volOff;

  // zero the w-halo pad columns once (never overwritten)
  if (tid < 2 * ROWS_LDS) {
    const int t_ = tid >> 3, r8 = tid & 7;
    lds[t_][r8][3] = 0.f;
    lds[t_][r8][164] = 0.f;
  }

  // ---- staging slot decode (loop-invariant); float4-ONLY global loads ----
  const float* gs[3];
  float* dst[3];
  bool rok[3], sok[3];
#pragma unroll
  for (int u = 0; u < 3; ++u) {
    const int i = tid + 256 * u;
    const bool ok = (i < SLOTS);
    const int ic = ok ? i : 0;
    const int t_ = ic >= SLOTS / 2;
    const int idx = ic - (t_ ? SLOTS / 2 : 0);
    const int r8 = idx / STRIPS, s = idx - r8 * STRIPS;
    const int hh = h0 - 1 + r8;
    const bool rv = ok && ((unsigned)hh < (unsigned)Hd);
    rok[u] = rv;
    sok[u] = ok;
    gs[u] = (t_ ? tb : pb) + (size_t)(rv ? hh : 0) * Wd + s * 4;
    dst[u] = &lds[t_][r8][4 + s * 4];
  }

  float4 rg[3];
  auto GLOAD = [&](int dsl) {            // issue 3 coalesced float4 loads
    const bool dok = (unsigned)dsl < (unsigned)Dd;
    const size_t so = (size_t)dsl * HW;
#pragma unroll
    for (int u = 0; u < 3; ++u) {
      float4 v = make_float4(0.f, 0.f, 0.f, 0.f);
      if (dok && rok[u]) v = *reinterpret_cast<const float4*>(gs[u] + so);
      rg[u] = v;
    }
  };
  auto DSW = [&]() {                     // consume: write to LDS
#pragma unroll
    for (int u = 0; u < 3; ++u)
      if (sok[u]) *reinterpret_cast<float4*>(dst[u]) = rg[u];
  };

  // ---- compute-thread decode ----
  const int cr = tid / STRIPS;           // 0..5 for tid<240
  const int cs = tid - cr * STRIPS;
  const int w0 = cs * 4;
  const bool is_c = (tid < CTHREADS);

  // rolling state [slot][tensor]
  float A[3][2][4], B[3][2][4], C[3][2][4];

  auto ABC = [&](int slot) {
#pragma unroll
    for (int t_ = 0; t_ < 2; ++t_) {
      float sw[3][4], dwv[3][4];
#pragma unroll
      for (int rr = 0; rr < 3; ++rr) {
        const float* row = &lds[t_][cr + rr][0];
        const float4 m = *reinterpret_cast<const float4*>(row + 4 + w0);
        const float xl = row[3 + w0], xr = row[8 + w0];
        const float x[6] = {xl, m.x, m.y, m.z, m.w, xr};
#pragma unroll
        for (int j = 0; j < 4; ++j) {
          sw[rr][j]  = x[j] + 2.f * x[j + 1] + x[j + 2];
          dwv[rr][j] = x[j + 2] - x[j];
        }
      }
#pragma unroll
      for (int j = 0; j < 4; ++j) {
        A[slot][t_][j] = sw[0][j] + 2.f * sw[1][j] + sw[2][j];
        B[slot][t_][j] = dwv[0][j] + 2.f * dwv[1][j] + dwv[2][j];
        C[slot][t_][j] = sw[2][j] - sw[0][j];
      }
    }
  };

  float acc = 0.f;

  // ---- prologue: slices d0-1 (slot0) and d0 (slot1) ----
  GLOAD(d0 - 1);
  DSW(); GLOAD(d0); __syncthreads();
  if (is_c) ABC(0);
  __syncthreads();
  DSW(); GLOAD(d0 + 1); __syncthreads();
  if (is_c) ABC(1);
  __syncthreads();

  // ---- main loop, fully unrolled: output slice d0+k ----
#pragma unroll
  for (int k = 0; k < DCHUNK; ++k) {
    DSW();                               // LDS <- slice d0+1+k (loaded last iter)
    if (k < DCHUNK - 1) GLOAD(d0 + 2 + k);  // issue next; consumed next iter top
    __syncthreads();
    const int i0 = k % 3, i1 = (k + 1) % 3, i2 = (k + 2) % 3;
    if (is_c) {
      ABC(i2);                           // state <- slice d0+1+k
#pragma unroll
      for (int j = 0; j < 4; ++j) {
        float gx = B[i0][0][j] + 2.f * B[i1][0][j] + B[i2][0][j];
        float gy = C[i0][0][j] + 2.f * C[i1][0][j] + C[i2][0][j];
        float gz = A[i2][0][j] - A[i0][0][j];
        const float pm = sqrtf(fmaf(gx, gx, fmaf(gy, gy, fmaf(gz, gz, EPS))));
        gx = B[i0][1][j] + 2.f * B[i1][1][j] + B[i2][1][j];
        gy = C[i0][1][j] + 2.f * C[i1][1][j] + C[i2][1][j];
        gz = A[i2][1][j] - A[i0][1][j];
        const float tm = sqrtf(fmaf(gx, gx, fmaf(gy, gy, fmaf(gz, gz, EPS))));
        acc += fabsf(pm - tm);
      }
    }
    __syncthreads();
  }

  // ---- reduction: wave shfl -> LDS -> one atomic per block ----
  float sred = acc;
#pragma unroll
  for (int off = 32; off > 0; off >>= 1) sred += __shfl_down(sred, off, 64);
  __shared__ float wsum[THREADS / 64];
  const int lane = tid & 63;
  const int wid = tid >> 6;
  if (lane == 0) wsum[wid] = sred;
  __syncthreads();
  if (tid == 0) {
    float t = 0.f;
#pragma unroll
    for (int i = 0; i < THREADS / 64; ++i) t += wsum[i];
    atomicAdd(out, t * (1.0f / (float)((size_t)Bd * Dd * Hd * Wd)));
  }
}

extern "C" void kernel_launch(void* const* d_in, const int* in_sizes, int n_in,
                              void* d_out, int out_size, void* d_ws, size_t ws_size,
                              hipStream_t stream) {
  const float* pred = (const float*)d_in[0];
  const float* targ = (const float*)d_in[1];
  float* out = (float*)d_out;
  (void)in_sizes; (void)n_in; (void)out_size; (void)d_ws; (void)ws_size;

  hipMemsetAsync(out, 0, sizeof(float), stream);
  dim3 grid(RGROUPS, NCHUNK, Bd);
  sobel_loss_kernel<<<grid, THREADS, 0, stream>>>(pred, targ, out);
}

// Round 6
// 46.291 us; speedup vs baseline: 1.9373x; 1.0770x over previous
//
#include <hip/hip_runtime.h>

namespace {
constexpr int Wd = 160, Hd = 192, Dd = 160, Bd = 2;
constexpr int HW = Hd * Wd;
constexpr int THREADS = 256;               // 4 waves
constexpr int ROWS_OUT = 6;                // output rows per block
constexpr int ROWS_LDS = 8;                // staged rows incl. h-halo
constexpr int RS = 164;                    // x row stride (floats), data at [0..159]
constexpr int HS = 42;                     // halo array row stride
constexpr int STRIPS = Wd / 4;             // 40
constexpr int CTHREADS = ROWS_OUT * STRIPS;   // 240 compute threads
constexpr int SLOTS = 2 * ROWS_LDS * STRIPS;  // 640 staging tasks
constexpr int DCHUNK = 8;
constexpr int NCHUNK = Dd / DCHUNK;        // 20
constexpr int RGROUPS = Hd / ROWS_OUT;     // 32
constexpr float EPS = 1e-8f;
}

__global__ __launch_bounds__(THREADS) void sobel_loss_kernel(
    const float* __restrict__ pred, const float* __restrict__ targ,
    float* __restrict__ out) {
  __shared__ float lds[2][ROWS_LDS][RS];   // raw x, 10.5 KB
  __shared__ float xlh[2][ROWS_LDS][HS];   // xlh[t][r][s] = x[t][r][4s-1]
  __shared__ float xrh[2][ROWS_LDS][HS];   // xrh[t][r][s] = x[t][r][4s+4]
  const int tid = threadIdx.x;
  const int h0 = blockIdx.x * ROWS_OUT;
  const int d0 = blockIdx.y * DCHUNK;
  const size_t volOff = (size_t)blockIdx.z * Dd * HW;
  const float* pb = pred + volOff;
  const float* tb = targ + volOff;

  // zero boundary halo columns once (never written by staging)
  if (tid < 16) {
    xlh[tid >> 3][tid & 7][0] = 0.f;
  } else if (tid < 32) {
    const int q = tid - 16;
    xrh[q >> 3][q & 7][STRIPS - 1] = 0.f;
  }

  // ---- staging task decode (2.5 tasks/thread); float4-ONLY global loads ----
  const float* gs[3];
  float* dst[3];
  float* xlp[3];
  float* xrp[3];
  bool rok[3], sok[3];
#pragma unroll
  for (int u = 0; u < 3; ++u) {
    const int i = tid + 256 * u;
    const bool ok = (i < SLOTS);
    const int ic = ok ? i : 0;
    const int t_ = ic >= SLOTS / 2;
    const int idx = ic - (t_ ? SLOTS / 2 : 0);
    const int r8 = idx / STRIPS, s = idx - r8 * STRIPS;
    const int hh = h0 - 1 + r8;
    const bool rv = ok && ((unsigned)hh < (unsigned)Hd);
    rok[u] = rv;
    sok[u] = ok;
    gs[u] = (t_ ? tb : pb) + (size_t)(rv ? hh : 0) * Wd + s * 4;
    dst[u] = &lds[t_][r8][s * 4];
    xlp[u] = &xlh[t_][r8][s + 1];                       // s+1 in [1,40]
    xrp[u] = &xrh[t_][r8][(s == 0) ? (HS - 1) : (s - 1)];  // dummy col 41 for s==0
  }

  float4 rg[3];
  auto GLOAD = [&](int dsl) {            // issue 3 coalesced float4 loads
    const bool dok = (unsigned)dsl < (unsigned)Dd;
    const size_t so = (size_t)dsl * HW;
#pragma unroll
    for (int u = 0; u < 3; ++u) {
      float4 v = make_float4(0.f, 0.f, 0.f, 0.f);
      if (dok && rok[u]) v = *reinterpret_cast<const float4*>(gs[u] + so);
      rg[u] = v;
    }
  };
  auto DSW = [&]() {                     // consume: write x + halo duplicates
#pragma unroll
    for (int u = 0; u < 3; ++u) {
      if (sok[u]) {
        *reinterpret_cast<float4*>(dst[u]) = rg[u];
        *xlp[u] = rg[u].w;               // xl for strip s+1
        *xrp[u] = rg[u].x;               // xr for strip s-1
      }
    }
  };

  // ---- compute-thread decode ----
  const int cr = tid / STRIPS;           // 0..5 for tid<240
  const int cs = tid - cr * STRIPS;
  const int w0 = cs * 4;
  const bool is_c = (tid < CTHREADS);

  // rolling state [slot][tensor]
  float A[3][2][4], B[3][2][4], C[3][2][4];

  auto ABC = [&](int slot) {
#pragma unroll
    for (int t_ = 0; t_ < 2; ++t_) {
      float sw[3][4], dwv[3][4];
#pragma unroll
      for (int rr = 0; rr < 3; ++rr) {
        const float4 m = *reinterpret_cast<const float4*>(&lds[t_][cr + rr][w0]);
        const float xl = xlh[t_][cr + rr][cs];   // conflict-free: contiguous in cs
        const float xr = xrh[t_][cr + rr][cs];
        const float x[6] = {xl, m.x, m.y, m.z, m.w, xr};
#pragma unroll
        for (int j = 0; j < 4; ++j) {
          sw[rr][j]  = x[j] + 2.f * x[j + 1] + x[j + 2];
          dwv[rr][j] = x[j + 2] - x[j];
        }
      }
#pragma unroll
      for (int j = 0; j < 4; ++j) {
        A[slot][t_][j] = sw[0][j] + 2.f * sw[1][j] + sw[2][j];
        B[slot][t_][j] = dwv[0][j] + 2.f * dwv[1][j] + dwv[2][j];
        C[slot][t_][j] = sw[2][j] - sw[0][j];
      }
    }
  };

  float acc = 0.f;

  // ---- prologue: slices d0-1 (slot0) and d0 (slot1) ----
  GLOAD(d0 - 1);
  DSW(); GLOAD(d0); __syncthreads();
  if (is_c) ABC(0);
  __syncthreads();
  DSW(); GLOAD(d0 + 1); __syncthreads();
  if (is_c) ABC(1);
  __syncthreads();

  // ---- main loop, fully unrolled: output slice d0+k ----
#pragma unroll
  for (int k = 0; k < DCHUNK; ++k) {
    DSW();                               // LDS <- slice d0+1+k (loaded last iter)
    if (k < DCHUNK - 1) GLOAD(d0 + 2 + k);
    __syncthreads();
    const int i0 = k % 3, i1 = (k + 1) % 3, i2 = (k + 2) % 3;
    if (is_c) {
      ABC(i2);                           // state <- slice d0+1+k
#pragma unroll
      for (int j = 0; j < 4; ++j) {
        float gx = B[i0][0][j] + 2.f * B[i1][0][j] + B[i2][0][j];
        float gy = C[i0][0][j] + 2.f * C[i1][0][j] + C[i2][0][j];
        float gz = A[i2][0][j] - A[i0][0][j];
        const float pm = sqrtf(fmaf(gx, gx, fmaf(gy, gy, fmaf(gz, gz, EPS))));
        gx = B[i0][1][j] + 2.f * B[i1][1][j] + B[i2][1][j];
        gy = C[i0][1][j] + 2.f * C[i1][1][j] + C[i2][1][j];
        gz = A[i2][1][j] - A[i0][1][j];
        const float tm = sqrtf(fmaf(gx, gx, fmaf(gy, gy, fmaf(gz, gz, EPS))));
        acc += fabsf(pm - tm);
      }
    }
    __syncthreads();
  }

  // ---- reduction: wave shfl -> LDS -> one atomic per block ----
  float sred = acc;
#pragma unroll
  for (int off = 32; off > 0; off >>= 1) sred += __shfl_down(sred, off, 64);
  __shared__ float wsum[THREADS / 64];
  const int lane = tid & 63;
  const int wid = tid >> 6;
  if (lane == 0) wsum[wid] = sred;
  __syncthreads();
  if (tid == 0) {
    float t = 0.f;
#pragma unroll
    for (int i = 0; i < THREADS / 64; ++i) t += wsum[i];
    atomicAdd(out, t * (1.0f / (float)((size_t)Bd * Dd * Hd * Wd)));
  }
}

extern "C" void kernel_launch(void* const* d_in, const int* in_sizes, int n_in,
                              void* d_out, int out_size, void* d_ws, size_t ws_size,
                              hipStream_t stream) {
  const float* pred = (const float*)d_in[0];
  const float* targ = (const float*)d_in[1];
  float* out = (float*)d_out;
  (void)in_sizes; (void)n_in; (void)out_size; (void)d_ws; (void)ws_size;

  hipMemsetAsync(out, 0, sizeof(float), stream);
  dim3 grid(RGROUPS, NCHUNK, Bd);
  sobel_loss_kernel<<<grid, THREADS, 0, stream>>>(pred, targ, out);
}